// Round 1
// baseline (11362.632 us; speedup 1.0000x reference)
//
#include <hip/hip_runtime.h>

#define N_NODES   100000
#define N_EDGES   1600000
#define D_EMB     128
#define ROUNDS    4
#define M_OUT     32
#define NUM_GRAPHS 512

// ---------------------------------------------------------------------------
// GEMM: out[n][128] = op( A[n][128] @ W[128][128] + b )
// MODE 0: out = relu(A@W + b)
// MODE 1: out = out + relu(A@W + b)   (residual update, in-place on `out`)
// Block: 256 threads, 32 rows per block. Thread (tr=tid>>5, tc=tid&31)
// computes 4 rows x 4 cols. A-tile in LDS (broadcast reads, conflict-free);
// W streamed float4 from global (64 KB, L2-resident).
// 100000 % 32 == 0, so no row guards needed.
// ---------------------------------------------------------------------------
template<int MODE>
__global__ __launch_bounds__(256) void gemm128_kernel(
    const float* __restrict__ A, const float* __restrict__ W,
    const float* __restrict__ bias, float* __restrict__ out)
{
    __shared__ float As[32][D_EMB];   // 16 KB

    const int tid = threadIdx.x;
    const int tc  = tid & 31;         // col group: cols 4*tc .. 4*tc+3
    const int tr  = tid >> 5;         // row group: rows 4*tr .. 4*tr+3
    const int r0  = blockIdx.x << 5;  // first row of tile

    // Load 32x128 A tile: 1024 float4, 4 per thread, fully coalesced.
    const float4* A4  = (const float4*)A;
    float4*       As4 = (float4*)&As[0][0];
    const int base4 = r0 << 5;        // r0 * 128 / 4
    #pragma unroll
    for (int i = 0; i < 4; ++i) {
        const int f = tid + (i << 8);
        As4[f] = A4[base4 + f];
    }
    __syncthreads();

    float acc[4][4];
    #pragma unroll
    for (int i = 0; i < 4; ++i)
        #pragma unroll
        for (int j = 0; j < 4; ++j) acc[i][j] = 0.f;

    const float4* W4 = (const float4*)W;
    #pragma unroll 8
    for (int k = 0; k < D_EMB; ++k) {
        const float4 w = W4[(k << 5) + tc];
        #pragma unroll
        for (int i = 0; i < 4; ++i) {
            const float a = As[(tr << 2) + i][k];
            acc[i][0] += a * w.x;
            acc[i][1] += a * w.y;
            acc[i][2] += a * w.z;
            acc[i][3] += a * w.w;
        }
    }

    const float4 bv = ((const float4*)bias)[tc];
    #pragma unroll
    for (int i = 0; i < 4; ++i) {
        const int row = r0 + (tr << 2) + i;
        float4 v;
        v.x = fmaxf(acc[i][0] + bv.x, 0.f);
        v.y = fmaxf(acc[i][1] + bv.y, 0.f);
        v.z = fmaxf(acc[i][2] + bv.z, 0.f);
        v.w = fmaxf(acc[i][3] + bv.w, 0.f);
        float4* op = (float4*)(out + (size_t)row * D_EMB) + tc;
        if (MODE == 1) {
            const float4 s = *op;
            v.x += s.x; v.y += s.y; v.z += s.z; v.w += s.w;
        }
        *op = v;
    }
}

// ---------------------------------------------------------------------------
// Edge scatter: agg[dst[e]] += msg[src[e]]   (128 floats per edge)
// 32 threads per edge, one float4 each, 4 hardware f32 atomics.
// ---------------------------------------------------------------------------
__global__ __launch_bounds__(256) void scatter_kernel(
    const float* __restrict__ msg, const int* __restrict__ src,
    const int* __restrict__ dst, float* __restrict__ agg)
{
    const unsigned gid = blockIdx.x * 256u + threadIdx.x;
    const unsigned e = gid >> 5;
    const unsigned j = gid & 31;
    const int s = src[e];
    const int d = dst[e];
    const float4 m = ((const float4*)msg)[(size_t)s * 32 + j];
    float* ap = agg + (size_t)d * D_EMB + (j << 2);
    unsafeAtomicAdd(ap + 0, m.x);
    unsafeAtomicAdd(ap + 1, m.y);
    unsafeAtomicAdd(ap + 2, m.z);
    unsafeAtomicAdd(ap + 3, m.w);
}

// ---------------------------------------------------------------------------
// Pool: gs[batch[n]] += state[n]. batch is sorted, so accumulate runs in
// registers and flush one atomic per (graph-boundary, column).
// Block: 256 threads = 128 cols x 2 row-halves; 64 node-rows per block.
// Per step, a 128-lane group reads one full coalesced row.
// ---------------------------------------------------------------------------
__global__ __launch_bounds__(256) void pool_kernel(
    const float* __restrict__ state, const int* __restrict__ batch,
    float* __restrict__ gs)
{
    const int tid = threadIdx.x;
    const int c = tid & 127;
    const int h = tid >> 7;
    const int n0 = blockIdx.x * 64 + h * 32;

    float acc = 0.f;
    int cur = -1;
    for (int i = 0; i < 32; ++i) {
        const int n = n0 + i;
        if (n >= N_NODES) break;
        const int bb = batch[n];   // wave-uniform
        if (bb != cur) {
            if (cur >= 0) unsafeAtomicAdd(&gs[cur * D_EMB + c], acc);
            cur = bb;
            acc = 0.f;
        }
        acc += state[(size_t)n * D_EMB + c];
    }
    if (cur >= 0) unsafeAtomicAdd(&gs[cur * D_EMB + c], acc);
}

// ---------------------------------------------------------------------------
// Output GEMM: out[512][32] = gs[512][128] @ out_W[128][32] + out_b
// One thread per output element.
// ---------------------------------------------------------------------------
__global__ __launch_bounds__(256) void out_kernel(
    const float* __restrict__ gs, const float* __restrict__ W,
    const float* __restrict__ bias, float* __restrict__ out)
{
    const int idx = blockIdx.x * 256 + threadIdx.x;
    const int g = idx >> 5;
    const int m = idx & 31;
    float acc = 0.f;
    #pragma unroll 8
    for (int k = 0; k < D_EMB; ++k)
        acc += gs[g * D_EMB + k] * W[k * M_OUT + m];
    out[idx] = acc + bias[m];
}

// ---------------------------------------------------------------------------
extern "C" void kernel_launch(void* const* d_in, const int* in_sizes, int n_in,
                              void* d_out, int out_size, void* d_ws, size_t ws_size,
                              hipStream_t stream)
{
    const float* x     = (const float*)d_in[0];
    const int*   eidx  = (const int*)d_in[1];
    const int*   batch = (const int*)d_in[2];
    const float* emb_W = (const float*)d_in[3];
    const float* emb_b = (const float*)d_in[4];
    const float* msg_W = (const float*)d_in[5];   // [4][128][128]
    const float* msg_b = (const float*)d_in[6];   // [4][128]
    const float* upd_W = (const float*)d_in[7];
    const float* upd_b = (const float*)d_in[8];
    const float* out_W = (const float*)d_in[9];
    const float* out_b = (const float*)d_in[10];
    float* out = (float*)d_out;

    const int* src = eidx;
    const int* dst = eidx + N_EDGES;

    // workspace layout (floats): state | msg | agg | gs  -> ~154 MB
    float* state = (float*)d_ws;
    float* msg   = state + (size_t)N_NODES * D_EMB;
    float* agg   = msg   + (size_t)N_NODES * D_EMB;
    float* gs    = agg   + (size_t)N_NODES * D_EMB;

    const dim3 blk(256);
    const int gemm_grid = N_NODES / 32;                 // 3125 (exact)
    const int scat_grid = (N_EDGES * 32) / 256;         // 200000 (exact)

    // state = relu(x @ emb_W + emb_b)
    gemm128_kernel<0><<<gemm_grid, blk, 0, stream>>>(x, emb_W, emb_b, state);

    for (int r = 0; r < ROUNDS; ++r) {
        // msg = relu(state @ msg_W[r] + msg_b[r])
        gemm128_kernel<0><<<gemm_grid, blk, 0, stream>>>(
            state, msg_W + (size_t)r * D_EMB * D_EMB, msg_b + (size_t)r * D_EMB, msg);
        // agg = scatter_add(msg[src] -> dst)
        hipMemsetAsync(agg, 0, (size_t)N_NODES * D_EMB * sizeof(float), stream);
        scatter_kernel<<<scat_grid, blk, 0, stream>>>(msg, src, dst, agg);
        // state += relu(agg @ upd_W[r] + upd_b[r])
        gemm128_kernel<1><<<gemm_grid, blk, 0, stream>>>(
            agg, upd_W + (size_t)r * D_EMB * D_EMB, upd_b + (size_t)r * D_EMB, state);
    }

    // graph pooling
    hipMemsetAsync(gs, 0, (size_t)NUM_GRAPHS * D_EMB * sizeof(float), stream);
    pool_kernel<<<(N_NODES + 63) / 64, blk, 0, stream>>>(state, batch, gs);

    // out = gs @ out_W + out_b
    out_kernel<<<(NUM_GRAPHS * M_OUT) / 256, blk, 0, stream>>>(gs, out_W, out_b, out);
}

// Round 2
// 1205.109 us; speedup vs baseline: 9.4287x; 9.4287x over previous
//
#include <hip/hip_runtime.h>

#define N_NODES    100000
#define N_EDGES    1600000
#define D_EMB      128
#define ROUNDS     4
#define M_OUT      32
#define NUM_GRAPHS 512

#define SCAN_ELEMS_PER_BLOCK 1024          // 256 threads x 4 elems
#define SCAN_NBLK ((N_NODES + SCAN_ELEMS_PER_BLOCK - 1) / SCAN_ELEMS_PER_BLOCK)  // 98

// ---------------------------------------------------------------------------
// GEMM: out[n][128] = op( A[n][128] @ W[128][128] + b )
// MODE 0: out = relu(A@W + b);  MODE 1: out += relu(A@W + b)
// ---------------------------------------------------------------------------
template<int MODE>
__global__ __launch_bounds__(256) void gemm128_kernel(
    const float* __restrict__ A, const float* __restrict__ W,
    const float* __restrict__ bias, float* __restrict__ out)
{
    __shared__ float As[32][D_EMB];   // 16 KB

    const int tid = threadIdx.x;
    const int tc  = tid & 31;
    const int tr  = tid >> 5;
    const int r0  = blockIdx.x << 5;

    const float4* A4  = (const float4*)A;
    float4*       As4 = (float4*)&As[0][0];
    const int base4 = r0 << 5;
    #pragma unroll
    for (int i = 0; i < 4; ++i) {
        const int f = tid + (i << 8);
        As4[f] = A4[base4 + f];
    }
    __syncthreads();

    float acc[4][4];
    #pragma unroll
    for (int i = 0; i < 4; ++i)
        #pragma unroll
        for (int j = 0; j < 4; ++j) acc[i][j] = 0.f;

    const float4* W4 = (const float4*)W;
    #pragma unroll 8
    for (int k = 0; k < D_EMB; ++k) {
        const float4 w = W4[(k << 5) + tc];
        #pragma unroll
        for (int i = 0; i < 4; ++i) {
            const float a = As[(tr << 2) + i][k];
            acc[i][0] += a * w.x;
            acc[i][1] += a * w.y;
            acc[i][2] += a * w.z;
            acc[i][3] += a * w.w;
        }
    }

    const float4 bv = ((const float4*)bias)[tc];
    #pragma unroll
    for (int i = 0; i < 4; ++i) {
        const int row = r0 + (tr << 2) + i;
        float4 v;
        v.x = fmaxf(acc[i][0] + bv.x, 0.f);
        v.y = fmaxf(acc[i][1] + bv.y, 0.f);
        v.z = fmaxf(acc[i][2] + bv.z, 0.f);
        v.w = fmaxf(acc[i][3] + bv.w, 0.f);
        float4* op = (float4*)(out + (size_t)row * D_EMB) + tc;
        if (MODE == 1) {
            const float4 s = *op;
            v.x += s.x; v.y += s.y; v.z += s.z; v.w += s.w;
        }
        *op = v;
    }
}

// ---------------------------------------------------------------------------
// CSR build step 1: degree histogram over dst
// ---------------------------------------------------------------------------
__global__ __launch_bounds__(256) void hist_kernel(
    const int* __restrict__ dst, int* __restrict__ deg)
{
    const int e = blockIdx.x * 256 + threadIdx.x;
    if (e < N_EDGES) atomicAdd(&deg[dst[e]], 1);
}

// ---------------------------------------------------------------------------
// CSR build step 2a: per-block exclusive scan (256 thr x 4 elems = 1024/block)
// ---------------------------------------------------------------------------
__global__ __launch_bounds__(256) void scan_local_kernel(
    const int* __restrict__ deg, int* __restrict__ rp, int* __restrict__ partials)
{
    __shared__ int sm[256];
    const int tid  = threadIdx.x;
    const int base = blockIdx.x * SCAN_ELEMS_PER_BLOCK + tid * 4;

    int v0 = (base + 0 < N_NODES) ? deg[base + 0] : 0;
    int v1 = (base + 1 < N_NODES) ? deg[base + 1] : 0;
    int v2 = (base + 2 < N_NODES) ? deg[base + 2] : 0;
    int v3 = (base + 3 < N_NODES) ? deg[base + 3] : 0;
    const int tot = v0 + v1 + v2 + v3;

    sm[tid] = tot;
    __syncthreads();
    #pragma unroll
    for (int off = 1; off < 256; off <<= 1) {
        const int x = (tid >= off) ? sm[tid - off] : 0;
        __syncthreads();
        sm[tid] += x;
        __syncthreads();
    }
    const int bex = sm[tid] - tot;   // exclusive prefix within block

    if (base + 0 < N_NODES) rp[base + 0] = bex;
    if (base + 1 < N_NODES) rp[base + 1] = bex + v0;
    if (base + 2 < N_NODES) rp[base + 2] = bex + v0 + v1;
    if (base + 3 < N_NODES) rp[base + 3] = bex + v0 + v1 + v2;
    if (tid == 255) partials[blockIdx.x] = sm[255];
}

// ---------------------------------------------------------------------------
// CSR build step 2b: exclusive scan of the block partials (single block)
// ---------------------------------------------------------------------------
__global__ __launch_bounds__(128) void scan_partials_kernel(int* __restrict__ partials)
{
    __shared__ int sm[128];
    const int tid = threadIdx.x;
    const int v = (tid < SCAN_NBLK) ? partials[tid] : 0;
    sm[tid] = v;
    __syncthreads();
    #pragma unroll
    for (int off = 1; off < 128; off <<= 1) {
        const int x = (tid >= off) ? sm[tid - off] : 0;
        __syncthreads();
        sm[tid] += x;
        __syncthreads();
    }
    if (tid < SCAN_NBLK) partials[tid] = sm[tid] - v;
}

// ---------------------------------------------------------------------------
// CSR build step 2c: add block offsets; also writes rp[N_NODES] and pos copy
// ---------------------------------------------------------------------------
__global__ __launch_bounds__(256) void scan_fixup_kernel(
    int* __restrict__ rp, const int* __restrict__ partials, int* __restrict__ pos)
{
    const int i = blockIdx.x * 256 + threadIdx.x;
    if (i < N_NODES) {
        const int v = rp[i] + partials[i >> 10];
        rp[i] = v;
        pos[i] = v;
    }
    if (i == 0) rp[N_NODES] = N_EDGES;
}

// ---------------------------------------------------------------------------
// CSR build step 3: bucket-fill src ids sorted by dst
// ---------------------------------------------------------------------------
__global__ __launch_bounds__(256) void fill_kernel(
    const int* __restrict__ src, const int* __restrict__ dst,
    int* __restrict__ pos, int* __restrict__ esrc)
{
    const int e = blockIdx.x * 256 + threadIdx.x;
    if (e < N_EDGES) {
        const int idx = atomicAdd(&pos[dst[e]], 1);
        esrc[idx] = src[e];
    }
}

// ---------------------------------------------------------------------------
// Aggregation as a gather: agg[n] = sum over incoming edges of msg[src]
// 32 lanes per node (one float4 per lane), 8 nodes per 256-thread block.
// No atomics; every agg row written exactly once (degree-0 rows get 0).
// ---------------------------------------------------------------------------
__global__ __launch_bounds__(256) void gather_kernel(
    const float* __restrict__ msg, const int* __restrict__ rp,
    const int* __restrict__ esrc, float* __restrict__ agg)
{
    const int tid = threadIdx.x;
    const int j   = tid & 31;
    const int n   = blockIdx.x * 8 + (tid >> 5);
    if (n >= N_NODES) return;

    const int beg = rp[n];
    const int end = rp[n + 1];
    const float4* m4 = (const float4*)msg;

    float4 a0 = make_float4(0.f, 0.f, 0.f, 0.f);
    float4 a1 = make_float4(0.f, 0.f, 0.f, 0.f);
    int i = beg;
    for (; i + 1 < end; i += 2) {
        const int s0 = esrc[i];
        const int s1 = esrc[i + 1];
        const float4 m0 = m4[(size_t)s0 * 32 + j];
        const float4 m1 = m4[(size_t)s1 * 32 + j];
        a0.x += m0.x; a0.y += m0.y; a0.z += m0.z; a0.w += m0.w;
        a1.x += m1.x; a1.y += m1.y; a1.z += m1.z; a1.w += m1.w;
    }
    if (i < end) {
        const float4 m0 = m4[(size_t)esrc[i] * 32 + j];
        a0.x += m0.x; a0.y += m0.y; a0.z += m0.z; a0.w += m0.w;
    }
    a0.x += a1.x; a0.y += a1.y; a0.z += a1.z; a0.w += a1.w;
    ((float4*)agg)[(size_t)n * 32 + j] = a0;
}

// ---------------------------------------------------------------------------
// Pool: gs[batch[n]] += state[n], batch sorted -> register run accumulation
// ---------------------------------------------------------------------------
__global__ __launch_bounds__(256) void pool_kernel(
    const float* __restrict__ state, const int* __restrict__ batch,
    float* __restrict__ gs)
{
    const int tid = threadIdx.x;
    const int c = tid & 127;
    const int h = tid >> 7;
    const int n0 = blockIdx.x * 64 + h * 32;

    float acc = 0.f;
    int cur = -1;
    for (int i = 0; i < 32; ++i) {
        const int n = n0 + i;
        if (n >= N_NODES) break;
        const int bb = batch[n];
        if (bb != cur) {
            if (cur >= 0) unsafeAtomicAdd(&gs[cur * D_EMB + c], acc);
            cur = bb;
            acc = 0.f;
        }
        acc += state[(size_t)n * D_EMB + c];
    }
    if (cur >= 0) unsafeAtomicAdd(&gs[cur * D_EMB + c], acc);
}

// ---------------------------------------------------------------------------
// Output GEMM: out[512][32] = gs[512][128] @ out_W[128][32] + out_b
// ---------------------------------------------------------------------------
__global__ __launch_bounds__(256) void out_kernel(
    const float* __restrict__ gs, const float* __restrict__ W,
    const float* __restrict__ bias, float* __restrict__ out)
{
    const int idx = blockIdx.x * 256 + threadIdx.x;
    const int g = idx >> 5;
    const int m = idx & 31;
    float acc = 0.f;
    #pragma unroll 8
    for (int k = 0; k < D_EMB; ++k)
        acc += gs[g * D_EMB + k] * W[k * M_OUT + m];
    out[idx] = acc + bias[m];
}

// ---------------------------------------------------------------------------
extern "C" void kernel_launch(void* const* d_in, const int* in_sizes, int n_in,
                              void* d_out, int out_size, void* d_ws, size_t ws_size,
                              hipStream_t stream)
{
    const float* x     = (const float*)d_in[0];
    const int*   eidx  = (const int*)d_in[1];
    const int*   batch = (const int*)d_in[2];
    const float* emb_W = (const float*)d_in[3];
    const float* emb_b = (const float*)d_in[4];
    const float* msg_W = (const float*)d_in[5];
    const float* msg_b = (const float*)d_in[6];
    const float* upd_W = (const float*)d_in[7];
    const float* upd_b = (const float*)d_in[8];
    const float* out_W = (const float*)d_in[9];
    const float* out_b = (const float*)d_in[10];
    float* out = (float*)d_out;

    const int* src = eidx;
    const int* dst = eidx + N_EDGES;

    // workspace layout (floats):
    //   state | msg | agg | gs | rp(100001) | esrc(1.6M) | partials(128)
    // deg aliases msg, pos aliases agg (both only used during CSR build,
    // which completes before msg/agg are first written).
    float* state = (float*)d_ws;
    float* msg   = state + (size_t)N_NODES * D_EMB;
    float* agg   = msg   + (size_t)N_NODES * D_EMB;
    float* gs    = agg   + (size_t)N_NODES * D_EMB;
    int*   rp       = (int*)(gs + (size_t)NUM_GRAPHS * D_EMB);
    int*   esrc     = rp + (N_NODES + 1);
    int*   partials = esrc + N_EDGES;
    int*   deg = (int*)msg;
    int*   pos = (int*)agg;

    const dim3 blk(256);

    // ---- CSR build (every launch; deterministic work) ----
    hipMemsetAsync(deg, 0, (size_t)N_NODES * sizeof(int), stream);
    hist_kernel<<<(N_EDGES + 255) / 256, blk, 0, stream>>>(dst, deg);
    scan_local_kernel<<<SCAN_NBLK, blk, 0, stream>>>(deg, rp, partials);
    scan_partials_kernel<<<1, 128, 0, stream>>>(partials);
    scan_fixup_kernel<<<(SCAN_NBLK * SCAN_ELEMS_PER_BLOCK) / 256, blk, 0, stream>>>(rp, partials, pos);
    fill_kernel<<<(N_EDGES + 255) / 256, blk, 0, stream>>>(src, dst, pos, esrc);

    // ---- network ----
    const int gemm_grid = N_NODES / 32;   // 3125
    gemm128_kernel<0><<<gemm_grid, blk, 0, stream>>>(x, emb_W, emb_b, state);

    for (int r = 0; r < ROUNDS; ++r) {
        gemm128_kernel<0><<<gemm_grid, blk, 0, stream>>>(
            state, msg_W + (size_t)r * D_EMB * D_EMB, msg_b + (size_t)r * D_EMB, msg);
        gather_kernel<<<(N_NODES + 7) / 8, blk, 0, stream>>>(msg, rp, esrc, agg);
        gemm128_kernel<1><<<gemm_grid, blk, 0, stream>>>(
            agg, upd_W + (size_t)r * D_EMB * D_EMB, upd_b + (size_t)r * D_EMB, state);
    }

    hipMemsetAsync(gs, 0, (size_t)NUM_GRAPHS * D_EMB * sizeof(float), stream);
    pool_kernel<<<(N_NODES + 63) / 64, blk, 0, stream>>>(state, batch, gs);
    out_kernel<<<(NUM_GRAPHS * M_OUT) / 256, blk, 0, stream>>>(gs, out_W, out_b, out);
}

// Round 3
// 700.807 us; speedup vs baseline: 16.2136x; 1.7196x over previous
//
#include <hip/hip_runtime.h>

#define N_NODES    100000
#define N_EDGES    1600000
#define D_EMB      128
#define ROUNDS     4
#define M_OUT      32
#define NUM_GRAPHS 512

#define SCAN_ELEMS_PER_BLOCK 1024
#define SCAN_NBLK ((N_NODES + SCAN_ELEMS_PER_BLOCK - 1) / SCAN_ELEMS_PER_BLOCK)  // 98

typedef __attribute__((ext_vector_type(8))) short short8;
typedef __attribute__((ext_vector_type(4))) float f32x4;

static __device__ __forceinline__ unsigned short f2bf(float f) {
    union { float f; unsigned u; } v; v.f = f;
    unsigned u = v.u;
    unsigned r = (u + 0x7FFFu + ((u >> 16) & 1u)) >> 16;   // RNE
    return (unsigned short)r;
}
static __device__ __forceinline__ float bf2f(unsigned short h) {
    union { unsigned u; float f; } v; v.u = ((unsigned)h) << 16;
    return v.f;
}

// ---------------------------------------------------------------------------
// Weight prep: WTall[mi][n][k] = bf16( W_mi[k][n] )  (transposed for 16B
// contiguous B-fragments). mi: 0=emb, 1..4=msg[r], 5..8=upd[r].
// ---------------------------------------------------------------------------
__global__ __launch_bounds__(256) void prep_weights_kernel(
    const float* __restrict__ emb_W, const float* __restrict__ msg_W,
    const float* __restrict__ upd_W, unsigned short* __restrict__ WTall)
{
    const int mi = blockIdx.x;
    const float* W = (mi == 0) ? emb_W
                   : (mi <= 4) ? msg_W + (size_t)(mi - 1) * D_EMB * D_EMB
                               : upd_W + (size_t)(mi - 5) * D_EMB * D_EMB;
    unsigned short* WT = WTall + (size_t)mi * D_EMB * D_EMB;
    for (int idx = threadIdx.x; idx < D_EMB * D_EMB; idx += 256) {
        const int n = idx >> 7, k = idx & 127;
        WT[idx] = f2bf(W[k * D_EMB + n]);
    }
}

// ---------------------------------------------------------------------------
// bf16 MFMA GEMM, 32 rows/block, 256 thr = 4 waves, wave w covers cols
// [32w, 32w+32). mfma_f32_16x16x32_bf16, K=128 fully unrolled (4 K-steps).
// A/B frag: elem i of lane -> k = (lane>>4)*8 + i; m/n = lane&15.
// D frag:   reg r of lane  -> row = (lane>>4)*4 + r; col = lane&15.
// MODE 0: out_bf16 = bf16(relu(AW+b))                       (msg)
// MODE 1: state_f32 += relu(AW+b); out_bf16 = bf16(state)   (update)
// MODE 2: state_f32 = relu(AW+b);  out_bf16 = bf16(state)   (embed)
// ---------------------------------------------------------------------------
template<int MODE, bool AF32>
__global__ __launch_bounds__(256) void gemm_mfma_kernel(
    const void* __restrict__ Aptr, const unsigned short* __restrict__ WT,
    const float* __restrict__ bias, float* __restrict__ state_f32,
    unsigned short* __restrict__ out_bf16)
{
    __shared__ unsigned short As[32][136];   // +8 pad: row stride 272B (17x16B)

    const int tid = threadIdx.x;
    const int r0  = blockIdx.x * 32;

    if (AF32) {
        const float4* A4 = (const float4*)Aptr + (size_t)r0 * 32;
        #pragma unroll
        for (int i = 0; i < 4; ++i) {
            const int ch = tid + (i << 8);          // 1024 float4 chunks
            const int r = ch >> 5, c = (ch & 31) << 2;
            const float4 f = A4[ch];
            ushort4 h;
            h.x = f2bf(f.x); h.y = f2bf(f.y); h.z = f2bf(f.z); h.w = f2bf(f.w);
            *(ushort4*)&As[r][c] = h;               // 8B ds_write
        }
    } else {
        const uint4* A4 = (const uint4*)((const unsigned short*)Aptr + (size_t)r0 * D_EMB);
        #pragma unroll
        for (int i = 0; i < 2; ++i) {
            const int ch = tid + (i << 8);          // 512 16B chunks
            const int r = ch >> 4, c = (ch & 15) << 3;
            *(uint4*)&As[r][c] = A4[ch];            // 16B ds_write
        }
    }
    __syncthreads();

    const int lane = tid & 63;
    const int w    = tid >> 6;
    const int m    = lane & 15;
    const int g    = lane >> 4;

    short8 a[2][4];
    #pragma unroll
    for (int rt = 0; rt < 2; ++rt)
        #pragma unroll
        for (int ks = 0; ks < 4; ++ks)
            a[rt][ks] = *(const short8*)&As[rt * 16 + m][ks * 32 + g * 8];

    short8 b[2][4];
    #pragma unroll
    for (int ct = 0; ct < 2; ++ct) {
        const int n = w * 32 + ct * 16 + m;
        #pragma unroll
        for (int ks = 0; ks < 4; ++ks)
            b[ct][ks] = *(const short8*)&WT[n * D_EMB + ks * 32 + g * 8];
    }

    f32x4 acc[2][2] = {};
    #pragma unroll
    for (int ks = 0; ks < 4; ++ks)
        #pragma unroll
        for (int rt = 0; rt < 2; ++rt)
            #pragma unroll
            for (int ct = 0; ct < 2; ++ct)
                acc[rt][ct] = __builtin_amdgcn_mfma_f32_16x16x32_bf16(
                    a[rt][ks], b[ct][ks], acc[rt][ct], 0, 0, 0);

    #pragma unroll
    for (int rt = 0; rt < 2; ++rt) {
        #pragma unroll
        for (int ct = 0; ct < 2; ++ct) {
            const int col = w * 32 + ct * 16 + m;
            const float bv = bias[col];
            #pragma unroll
            for (int r = 0; r < 4; ++r) {
                const int row = r0 + rt * 16 + g * 4 + r;
                const float v = fmaxf(acc[rt][ct][r] + bv, 0.f);
                const size_t idx = (size_t)row * D_EMB + col;
                if (MODE == 0) {
                    out_bf16[idx] = f2bf(v);
                } else if (MODE == 2) {
                    state_f32[idx] = v;
                    out_bf16[idx] = f2bf(v);
                } else {
                    const float s = state_f32[idx] + v;
                    state_f32[idx] = s;
                    out_bf16[idx] = f2bf(s);
                }
            }
        }
    }
}

// ---------------------------------------------------------------------------
// CSR build
// ---------------------------------------------------------------------------
__global__ __launch_bounds__(256) void hist_kernel(
    const int* __restrict__ dst, int* __restrict__ deg)
{
    const int e = blockIdx.x * 256 + threadIdx.x;
    if (e < N_EDGES) atomicAdd(&deg[dst[e]], 1);
}

__global__ __launch_bounds__(256) void scan_local_kernel(
    const int* __restrict__ deg, int* __restrict__ rp, int* __restrict__ partials)
{
    __shared__ int sm[256];
    const int tid  = threadIdx.x;
    const int base = blockIdx.x * SCAN_ELEMS_PER_BLOCK + tid * 4;

    int v0 = (base + 0 < N_NODES) ? deg[base + 0] : 0;
    int v1 = (base + 1 < N_NODES) ? deg[base + 1] : 0;
    int v2 = (base + 2 < N_NODES) ? deg[base + 2] : 0;
    int v3 = (base + 3 < N_NODES) ? deg[base + 3] : 0;
    const int tot = v0 + v1 + v2 + v3;

    sm[tid] = tot;
    __syncthreads();
    #pragma unroll
    for (int off = 1; off < 256; off <<= 1) {
        const int x = (tid >= off) ? sm[tid - off] : 0;
        __syncthreads();
        sm[tid] += x;
        __syncthreads();
    }
    const int bex = sm[tid] - tot;

    if (base + 0 < N_NODES) rp[base + 0] = bex;
    if (base + 1 < N_NODES) rp[base + 1] = bex + v0;
    if (base + 2 < N_NODES) rp[base + 2] = bex + v0 + v1;
    if (base + 3 < N_NODES) rp[base + 3] = bex + v0 + v1 + v2;
    if (tid == 255) partials[blockIdx.x] = sm[255];
}

__global__ __launch_bounds__(128) void scan_partials_kernel(int* __restrict__ partials)
{
    __shared__ int sm[128];
    const int tid = threadIdx.x;
    const int v = (tid < SCAN_NBLK) ? partials[tid] : 0;
    sm[tid] = v;
    __syncthreads();
    #pragma unroll
    for (int off = 1; off < 128; off <<= 1) {
        const int x = (tid >= off) ? sm[tid - off] : 0;
        __syncthreads();
        sm[tid] += x;
        __syncthreads();
    }
    if (tid < SCAN_NBLK) partials[tid] = sm[tid] - v;
}

__global__ __launch_bounds__(256) void scan_fixup_kernel(
    int* __restrict__ rp, const int* __restrict__ partials, int* __restrict__ pos)
{
    const int i = blockIdx.x * 256 + threadIdx.x;
    if (i < N_NODES) {
        const int v = rp[i] + partials[i >> 10];
        rp[i] = v;
        pos[i] = v;
    }
    if (i == 0) rp[N_NODES] = N_EDGES;
}

__global__ __launch_bounds__(256) void fill_kernel(
    const int* __restrict__ src, const int* __restrict__ dst,
    int* __restrict__ pos, int* __restrict__ esrc)
{
    const int e = blockIdx.x * 256 + threadIdx.x;
    if (e < N_EDGES) {
        const int idx = atomicAdd(&pos[dst[e]], 1);
        esrc[idx] = src[e];
    }
}

// ---------------------------------------------------------------------------
// Gather (bf16): agg[n] = sum msg[src]. 16 lanes/node, uint4 (8 bf16) each.
// ---------------------------------------------------------------------------
__global__ __launch_bounds__(256) void gather_bf16_kernel(
    const unsigned short* __restrict__ msg, const int* __restrict__ rp,
    const int* __restrict__ esrc, unsigned short* __restrict__ agg)
{
    const int tid = threadIdx.x;
    const int j   = tid & 15;
    const int n   = blockIdx.x * 16 + (tid >> 4);
    if (n >= N_NODES) return;

    const int beg = rp[n];
    const int end = rp[n + 1];
    const uint4* m4 = (const uint4*)msg;

    float a0[8] = {0,0,0,0,0,0,0,0};
    float a1[8] = {0,0,0,0,0,0,0,0};
    int i = beg;
    for (; i + 1 < end; i += 2) {
        const int s0 = esrc[i];
        const int s1 = esrc[i + 1];
        const uint4 v0 = m4[(size_t)s0 * 16 + j];
        const uint4 v1 = m4[(size_t)s1 * 16 + j];
        a0[0] += bf2f(v0.x & 0xffff); a0[1] += bf2f(v0.x >> 16);
        a0[2] += bf2f(v0.y & 0xffff); a0[3] += bf2f(v0.y >> 16);
        a0[4] += bf2f(v0.z & 0xffff); a0[5] += bf2f(v0.z >> 16);
        a0[6] += bf2f(v0.w & 0xffff); a0[7] += bf2f(v0.w >> 16);
        a1[0] += bf2f(v1.x & 0xffff); a1[1] += bf2f(v1.x >> 16);
        a1[2] += bf2f(v1.y & 0xffff); a1[3] += bf2f(v1.y >> 16);
        a1[4] += bf2f(v1.z & 0xffff); a1[5] += bf2f(v1.z >> 16);
        a1[6] += bf2f(v1.w & 0xffff); a1[7] += bf2f(v1.w >> 16);
    }
    if (i < end) {
        const uint4 v0 = m4[(size_t)esrc[i] * 16 + j];
        a0[0] += bf2f(v0.x & 0xffff); a0[1] += bf2f(v0.x >> 16);
        a0[2] += bf2f(v0.y & 0xffff); a0[3] += bf2f(v0.y >> 16);
        a0[4] += bf2f(v0.z & 0xffff); a0[5] += bf2f(v0.z >> 16);
        a0[6] += bf2f(v0.w & 0xffff); a0[7] += bf2f(v0.w >> 16);
    }
    #pragma unroll
    for (int t = 0; t < 8; ++t) a0[t] += a1[t];

    uint4 o;
    o.x = (unsigned)f2bf(a0[0]) | ((unsigned)f2bf(a0[1]) << 16);
    o.y = (unsigned)f2bf(a0[2]) | ((unsigned)f2bf(a0[3]) << 16);
    o.z = (unsigned)f2bf(a0[4]) | ((unsigned)f2bf(a0[5]) << 16);
    o.w = (unsigned)f2bf(a0[6]) | ((unsigned)f2bf(a0[7]) << 16);
    ((uint4*)agg)[(size_t)n * 16 + j] = o;
}

// ---------------------------------------------------------------------------
// Pool (reads fp32 state): gs[batch[n]] += state[n], batch sorted
// ---------------------------------------------------------------------------
__global__ __launch_bounds__(256) void pool_kernel(
    const float* __restrict__ state, const int* __restrict__ batch,
    float* __restrict__ gs)
{
    const int tid = threadIdx.x;
    const int c = tid & 127;
    const int h = tid >> 7;
    const int n0 = blockIdx.x * 64 + h * 32;

    float acc = 0.f;
    int cur = -1;
    for (int i = 0; i < 32; ++i) {
        const int n = n0 + i;
        if (n >= N_NODES) break;
        const int bb = batch[n];
        if (bb != cur) {
            if (cur >= 0) unsafeAtomicAdd(&gs[cur * D_EMB + c], acc);
            cur = bb;
            acc = 0.f;
        }
        acc += state[(size_t)n * D_EMB + c];
    }
    if (cur >= 0) unsafeAtomicAdd(&gs[cur * D_EMB + c], acc);
}

__global__ __launch_bounds__(256) void out_kernel(
    const float* __restrict__ gs, const float* __restrict__ W,
    const float* __restrict__ bias, float* __restrict__ out)
{
    const int idx = blockIdx.x * 256 + threadIdx.x;
    const int g = idx >> 5;
    const int m = idx & 31;
    float acc = 0.f;
    #pragma unroll 8
    for (int k = 0; k < D_EMB; ++k)
        acc += gs[g * D_EMB + k] * W[k * M_OUT + m];
    out[idx] = acc + bias[m];
}

// ---------------------------------------------------------------------------
extern "C" void kernel_launch(void* const* d_in, const int* in_sizes, int n_in,
                              void* d_out, int out_size, void* d_ws, size_t ws_size,
                              hipStream_t stream)
{
    const float* x     = (const float*)d_in[0];
    const int*   eidx  = (const int*)d_in[1];
    const int*   batch = (const int*)d_in[2];
    const float* emb_W = (const float*)d_in[3];
    const float* emb_b = (const float*)d_in[4];
    const float* msg_W = (const float*)d_in[5];
    const float* msg_b = (const float*)d_in[6];
    const float* upd_W = (const float*)d_in[7];
    const float* upd_b = (const float*)d_in[8];
    const float* out_W = (const float*)d_in[9];
    const float* out_b = (const float*)d_in[10];
    float* out = (float*)d_out;

    const int* src = eidx;
    const int* dst = eidx + N_EDGES;

    // workspace layout (16B-aligned carve):
    //   state_f32[12.8M f32] | state_bf16[12.8M u16] | msg_bf16 | agg_bf16 |
    //   gs[64K f32] | WTall[9*16384 u16] | rp[100001] | esrc[1.6M] | partials
    char* p = (char*)d_ws;
    float* state_f32 = (float*)p;                       p += (size_t)N_NODES * D_EMB * 4;
    unsigned short* state_bf16 = (unsigned short*)p;    p += (size_t)N_NODES * D_EMB * 2;
    unsigned short* msg_bf16 = (unsigned short*)p;      p += (size_t)N_NODES * D_EMB * 2;
    unsigned short* agg_bf16 = (unsigned short*)p;      p += (size_t)N_NODES * D_EMB * 2;
    float* gs = (float*)p;                              p += (size_t)NUM_GRAPHS * D_EMB * 4;
    unsigned short* WTall = (unsigned short*)p;         p += (size_t)9 * D_EMB * D_EMB * 2;
    int* rp = (int*)p;                                  p += (size_t)(N_NODES + 1) * 4;
    int* esrc = (int*)p;                                p += (size_t)N_EDGES * 4;
    int* partials = (int*)p;

    int* deg = (int*)msg_bf16;   // CSR-build-time aliases (dead afterwards)
    int* pos = (int*)agg_bf16;

    const dim3 blk(256);
    const int gemm_grid = N_NODES / 32;   // 3125

    // ---- weight prep + CSR build ----
    prep_weights_kernel<<<9, blk, 0, stream>>>(emb_W, msg_W, upd_W, WTall);
    hipMemsetAsync(deg, 0, (size_t)N_NODES * sizeof(int), stream);
    hist_kernel<<<(N_EDGES + 255) / 256, blk, 0, stream>>>(dst, deg);
    scan_local_kernel<<<SCAN_NBLK, blk, 0, stream>>>(deg, rp, partials);
    scan_partials_kernel<<<1, 128, 0, stream>>>(partials);
    scan_fixup_kernel<<<(SCAN_NBLK * SCAN_ELEMS_PER_BLOCK) / 256, blk, 0, stream>>>(rp, partials, pos);
    fill_kernel<<<(N_EDGES + 255) / 256, blk, 0, stream>>>(src, dst, pos, esrc);

    // ---- network ----
    gemm_mfma_kernel<2, true><<<gemm_grid, blk, 0, stream>>>(
        x, WTall, emb_b, state_f32, state_bf16);

    for (int r = 0; r < ROUNDS; ++r) {
        gemm_mfma_kernel<0, false><<<gemm_grid, blk, 0, stream>>>(
            state_bf16, WTall + (size_t)(1 + r) * D_EMB * D_EMB,
            msg_b + (size_t)r * D_EMB, nullptr, msg_bf16);
        gather_bf16_kernel<<<(N_NODES + 15) / 16, blk, 0, stream>>>(
            msg_bf16, rp, esrc, agg_bf16);
        gemm_mfma_kernel<1, false><<<gemm_grid, blk, 0, stream>>>(
            agg_bf16, WTall + (size_t)(5 + r) * D_EMB * D_EMB,
            upd_b + (size_t)r * D_EMB, state_f32, state_bf16);
    }

    hipMemsetAsync(gs, 0, (size_t)NUM_GRAPHS * D_EMB * sizeof(float), stream);
    pool_kernel<<<(N_NODES + 63) / 64, blk, 0, stream>>>(state_f32, batch, gs);
    out_kernel<<<(NUM_GRAPHS * M_OUT) / 256, blk, 0, stream>>>(gs, out_W, out_b, out);
}

// Round 4
// 572.283 us; speedup vs baseline: 19.8549x; 1.2246x over previous
//
#include <hip/hip_runtime.h>

#define N_NODES    100000
#define N_EDGES    1600000
#define D_EMB      128
#define ROUNDS     4
#define M_OUT      32
#define NUM_GRAPHS 512

#define NPASS      8
#define PASS_RANGE (N_NODES / NPASS)     // 12500, exact
#define GEMM_BLOCKS 1024
#define N_TILES    (N_NODES / 32)        // 3125, exact

#define SCAN_ELEMS_PER_BLOCK 1024
#define SCAN_NBLK ((N_NODES + SCAN_ELEMS_PER_BLOCK - 1) / SCAN_ELEMS_PER_BLOCK)  // 98

typedef __attribute__((ext_vector_type(8))) short short8;
typedef __attribute__((ext_vector_type(4))) float f32x4;

static __device__ __forceinline__ unsigned short f2bf(float f) {
    union { float f; unsigned u; } v; v.f = f;
    unsigned u = v.u;
    unsigned r = (u + 0x7FFFu + ((u >> 16) & 1u)) >> 16;   // RNE
    return (unsigned short)r;
}
static __device__ __forceinline__ float bf2f(unsigned short h) {
    union { unsigned u; float f; } v; v.u = ((unsigned)h) << 16;
    return v.f;
}

// ---------------------------------------------------------------------------
// Weight prep: WTall[mi][n][k] = bf16( W_mi[k][n] )
// ---------------------------------------------------------------------------
__global__ __launch_bounds__(256) void prep_weights_kernel(
    const float* __restrict__ emb_W, const float* __restrict__ msg_W,
    const float* __restrict__ upd_W, unsigned short* __restrict__ WTall)
{
    const int mi = blockIdx.x;
    const float* W = (mi == 0) ? emb_W
                   : (mi <= 4) ? msg_W + (size_t)(mi - 1) * D_EMB * D_EMB
                               : upd_W + (size_t)(mi - 5) * D_EMB * D_EMB;
    unsigned short* WT = WTall + (size_t)mi * D_EMB * D_EMB;
    for (int idx = threadIdx.x; idx < D_EMB * D_EMB; idx += 256) {
        const int n = idx >> 7, k = idx & 127;
        WT[idx] = f2bf(W[k * D_EMB + n]);
    }
}

// ---------------------------------------------------------------------------
// Looped bf16 MFMA GEMM. Each block strides over 32-row tiles; B fragments
// loaded once; A staging double-buffered in LDS (prefetch next tile into
// registers during current tile's MFMA).
// MODE 0: outb = bf16(relu(AW+b))                  (msg)
// MODE 1: state = bf16(state_old + relu(AW+b))     (update, in place)
// MODE 2: state = bf16(relu(AW+b))                 (embed, A is fp32 x)
// ---------------------------------------------------------------------------
template<int MODE, bool AF32>
__global__ __launch_bounds__(256) void gemm_loop_kernel(
    const void* __restrict__ Aptr, const unsigned short* __restrict__ WT,
    const float* __restrict__ bias, unsigned short* __restrict__ state,
    unsigned short* __restrict__ outb)
{
    __shared__ unsigned short As[2][32][136];   // +8 pad: row stride 272 B

    const int tid  = threadIdx.x;
    const int lane = tid & 63;
    const int w    = tid >> 6;
    const int m    = lane & 15;
    const int g    = lane >> 4;

    // B fragments: once per block
    short8 bfr[2][4];
    #pragma unroll
    for (int ct = 0; ct < 2; ++ct) {
        const int n = w * 32 + ct * 16 + m;
        #pragma unroll
        for (int ks = 0; ks < 4; ++ks)
            bfr[ct][ks] = *(const short8*)&WT[n * D_EMB + ks * 32 + g * 8];
    }
    const float bv0 = bias[w * 32 + m];
    const float bv1 = bias[w * 32 + 16 + m];

    int tile = blockIdx.x;

    // stage first tile -> As[0]
    if (AF32) {
        const float4* A4 = (const float4*)Aptr;
        #pragma unroll
        for (int i = 0; i < 4; ++i) {
            const int ch = tid + (i << 8);
            const float4 f = A4[(size_t)tile * 1024 + ch];
            ushort4 h; h.x = f2bf(f.x); h.y = f2bf(f.y); h.z = f2bf(f.z); h.w = f2bf(f.w);
            *(ushort4*)&As[0][ch >> 5][(ch & 31) << 2] = h;
        }
    } else {
        const uint4* A2 = (const uint4*)Aptr;
        #pragma unroll
        for (int i = 0; i < 2; ++i) {
            const int ch = tid + (i << 8);
            const uint4 v = A2[(size_t)tile * 512 + ch];
            *(uint4*)&As[0][ch >> 4][(ch & 15) << 3] = v;
        }
    }
    __syncthreads();

    int cur = 0;
    while (true) {
        const int next = tile + GEMM_BLOCKS;
        const bool have = next < N_TILES;

        // issue next tile's global loads into registers
        float4 rgf[4]; uint4 rgu[2];
        if (have) {
            if (AF32) {
                const float4* A4 = (const float4*)Aptr;
                #pragma unroll
                for (int i = 0; i < 4; ++i)
                    rgf[i] = A4[(size_t)next * 1024 + tid + (i << 8)];
            } else {
                const uint4* A2 = (const uint4*)Aptr;
                #pragma unroll
                for (int i = 0; i < 2; ++i)
                    rgu[i] = A2[(size_t)next * 512 + tid + (i << 8)];
            }
        }

        // A fragments + MFMA
        short8 a[2][4];
        #pragma unroll
        for (int rt = 0; rt < 2; ++rt)
            #pragma unroll
            for (int ks = 0; ks < 4; ++ks)
                a[rt][ks] = *(const short8*)&As[cur][rt * 16 + m][ks * 32 + g * 8];

        f32x4 acc[2][2] = {};
        #pragma unroll
        for (int ks = 0; ks < 4; ++ks)
            #pragma unroll
            for (int rt = 0; rt < 2; ++rt)
                #pragma unroll
                for (int ct = 0; ct < 2; ++ct)
                    acc[rt][ct] = __builtin_amdgcn_mfma_f32_16x16x32_bf16(
                        a[rt][ks], bfr[ct][ks], acc[rt][ct], 0, 0, 0);

        // write prefetched tile into other LDS buffer
        if (have) {
            if (AF32) {
                #pragma unroll
                for (int i = 0; i < 4; ++i) {
                    const int ch = tid + (i << 8);
                    ushort4 h;
                    h.x = f2bf(rgf[i].x); h.y = f2bf(rgf[i].y);
                    h.z = f2bf(rgf[i].z); h.w = f2bf(rgf[i].w);
                    *(ushort4*)&As[cur ^ 1][ch >> 5][(ch & 31) << 2] = h;
                }
            } else {
                #pragma unroll
                for (int i = 0; i < 2; ++i) {
                    const int ch = tid + (i << 8);
                    *(uint4*)&As[cur ^ 1][ch >> 4][(ch & 15) << 3] = rgu[i];
                }
            }
        }

        // epilogue for `tile`
        #pragma unroll
        for (int rt = 0; rt < 2; ++rt) {
            #pragma unroll
            for (int ct = 0; ct < 2; ++ct) {
                const int col = w * 32 + ct * 16 + m;
                const float bv = ct ? bv1 : bv0;
                #pragma unroll
                for (int r = 0; r < 4; ++r) {
                    const int row = tile * 32 + rt * 16 + g * 4 + r;
                    const size_t idx = (size_t)row * D_EMB + col;
                    const float v = fmaxf(acc[rt][ct][r] + bv, 0.f);
                    if (MODE == 0) {
                        outb[idx] = f2bf(v);
                    } else if (MODE == 2) {
                        state[idx] = f2bf(v);
                    } else {
                        const float s = bf2f(state[idx]) + v;
                        state[idx] = f2bf(s);
                    }
                }
            }
        }

        if (!have) break;
        __syncthreads();
        cur ^= 1;
        tile = next;
    }
}

// ---------------------------------------------------------------------------
// CSR build — XCD-confined multipass. Block b (round-robin -> XCD b&7)
// handles only dst in [ (b&7)*PASS_RANGE, +PASS_RANGE ), so the atomics and
// scattered writes for one dst-range stay in one XCD's L2 -> full-line
// writebacks instead of 16x amplification.
// ---------------------------------------------------------------------------
__global__ __launch_bounds__(256) void hist_mp_kernel(
    const int* __restrict__ dst, int* __restrict__ deg)
{
    const int p = blockIdx.x & 7;
    const int e = (blockIdx.x >> 3) * 256 + threadIdx.x;
    if (e < N_EDGES) {
        const int d = dst[e];
        if ((unsigned)(d - p * PASS_RANGE) < (unsigned)PASS_RANGE)
            atomicAdd(&deg[d], 1);
    }
}

__global__ __launch_bounds__(256) void scan_local_kernel(
    const int* __restrict__ deg, int* __restrict__ rp, int* __restrict__ partials)
{
    __shared__ int sm[256];
    const int tid  = threadIdx.x;
    const int base = blockIdx.x * SCAN_ELEMS_PER_BLOCK + tid * 4;

    int v0 = (base + 0 < N_NODES) ? deg[base + 0] : 0;
    int v1 = (base + 1 < N_NODES) ? deg[base + 1] : 0;
    int v2 = (base + 2 < N_NODES) ? deg[base + 2] : 0;
    int v3 = (base + 3 < N_NODES) ? deg[base + 3] : 0;
    const int tot = v0 + v1 + v2 + v3;

    sm[tid] = tot;
    __syncthreads();
    #pragma unroll
    for (int off = 1; off < 256; off <<= 1) {
        const int x = (tid >= off) ? sm[tid - off] : 0;
        __syncthreads();
        sm[tid] += x;
        __syncthreads();
    }
    const int bex = sm[tid] - tot;

    if (base + 0 < N_NODES) rp[base + 0] = bex;
    if (base + 1 < N_NODES) rp[base + 1] = bex + v0;
    if (base + 2 < N_NODES) rp[base + 2] = bex + v0 + v1;
    if (base + 3 < N_NODES) rp[base + 3] = bex + v0 + v1 + v2;
    if (tid == 255) partials[blockIdx.x] = sm[255];
}

__global__ __launch_bounds__(128) void scan_partials_kernel(int* __restrict__ partials)
{
    __shared__ int sm[128];
    const int tid = threadIdx.x;
    const int v = (tid < SCAN_NBLK) ? partials[tid] : 0;
    sm[tid] = v;
    __syncthreads();
    #pragma unroll
    for (int off = 1; off < 128; off <<= 1) {
        const int x = (tid >= off) ? sm[tid - off] : 0;
        __syncthreads();
        sm[tid] += x;
        __syncthreads();
    }
    if (tid < SCAN_NBLK) partials[tid] = sm[tid] - v;
}

__global__ __launch_bounds__(256) void scan_fixup_kernel(
    int* __restrict__ rp, const int* __restrict__ partials, int* __restrict__ pos)
{
    const int i = blockIdx.x * 256 + threadIdx.x;
    if (i < N_NODES) {
        const int v = rp[i] + partials[i >> 10];
        rp[i] = v;
        pos[i] = v;
    }
    if (i == 0) rp[N_NODES] = N_EDGES;
}

__global__ __launch_bounds__(256) void fill_mp_kernel(
    const int* __restrict__ src, const int* __restrict__ dst,
    int* __restrict__ pos, int* __restrict__ esrc)
{
    const int p = blockIdx.x & 7;
    const int e = (blockIdx.x >> 3) * 256 + threadIdx.x;
    if (e < N_EDGES) {
        const int d = dst[e];
        if ((unsigned)(d - p * PASS_RANGE) < (unsigned)PASS_RANGE) {
            const int idx = atomicAdd(&pos[d], 1);
            esrc[idx] = src[e];
        }
    }
}

// ---------------------------------------------------------------------------
// Gather (bf16): agg[n] = sum msg[src]. 16 lanes/node, uint4 (8 bf16) each.
// ---------------------------------------------------------------------------
__global__ __launch_bounds__(256) void gather_bf16_kernel(
    const unsigned short* __restrict__ msg, const int* __restrict__ rp,
    const int* __restrict__ esrc, unsigned short* __restrict__ agg)
{
    const int tid = threadIdx.x;
    const int j   = tid & 15;
    const int n   = blockIdx.x * 16 + (tid >> 4);
    if (n >= N_NODES) return;

    const int beg = rp[n];
    const int end = rp[n + 1];
    const uint4* m4 = (const uint4*)msg;

    float a0[8] = {0,0,0,0,0,0,0,0};
    float a1[8] = {0,0,0,0,0,0,0,0};
    int i = beg;
    for (; i + 1 < end; i += 2) {
        const int s0 = esrc[i];
        const int s1 = esrc[i + 1];
        const uint4 v0 = m4[(size_t)s0 * 16 + j];
        const uint4 v1 = m4[(size_t)s1 * 16 + j];
        a0[0] += bf2f(v0.x & 0xffff); a0[1] += bf2f(v0.x >> 16);
        a0[2] += bf2f(v0.y & 0xffff); a0[3] += bf2f(v0.y >> 16);
        a0[4] += bf2f(v0.z & 0xffff); a0[5] += bf2f(v0.z >> 16);
        a0[6] += bf2f(v0.w & 0xffff); a0[7] += bf2f(v0.w >> 16);
        a1[0] += bf2f(v1.x & 0xffff); a1[1] += bf2f(v1.x >> 16);
        a1[2] += bf2f(v1.y & 0xffff); a1[3] += bf2f(v1.y >> 16);
        a1[4] += bf2f(v1.z & 0xffff); a1[5] += bf2f(v1.z >> 16);
        a1[6] += bf2f(v1.w & 0xffff); a1[7] += bf2f(v1.w >> 16);
    }
    if (i < end) {
        const uint4 v0 = m4[(size_t)esrc[i] * 16 + j];
        a0[0] += bf2f(v0.x & 0xffff); a0[1] += bf2f(v0.x >> 16);
        a0[2] += bf2f(v0.y & 0xffff); a0[3] += bf2f(v0.y >> 16);
        a0[4] += bf2f(v0.z & 0xffff); a0[5] += bf2f(v0.z >> 16);
        a0[6] += bf2f(v0.w & 0xffff); a0[7] += bf2f(v0.w >> 16);
    }
    #pragma unroll
    for (int t = 0; t < 8; ++t) a0[t] += a1[t];

    uint4 o;
    o.x = (unsigned)f2bf(a0[0]) | ((unsigned)f2bf(a0[1]) << 16);
    o.y = (unsigned)f2bf(a0[2]) | ((unsigned)f2bf(a0[3]) << 16);
    o.z = (unsigned)f2bf(a0[4]) | ((unsigned)f2bf(a0[5]) << 16);
    o.w = (unsigned)f2bf(a0[6]) | ((unsigned)f2bf(a0[7]) << 16);
    ((uint4*)agg)[(size_t)n * 16 + j] = o;
}

// ---------------------------------------------------------------------------
// Pool (bf16 state): gs[batch[n]] += state[n]; batch sorted -> run accumulate.
// 256 thr = 4 groups x 64 lanes; lane covers 2 cols via one u32 load.
// ---------------------------------------------------------------------------
__global__ __launch_bounds__(256) void pool_kernel(
    const unsigned short* __restrict__ state, const int* __restrict__ batch,
    float* __restrict__ gs)
{
    const int lane = threadIdx.x & 63;
    const int grp  = threadIdx.x >> 6;
    const int n0 = blockIdx.x * 128 + grp * 32;
    const int c0 = lane * 2;

    float a0 = 0.f, a1 = 0.f;
    int cur = -1;
    for (int i = 0; i < 32; ++i) {
        const int n = n0 + i;
        if (n >= N_NODES) break;
        const int bb = batch[n];
        if (bb != cur) {
            if (cur >= 0) {
                unsafeAtomicAdd(&gs[cur * D_EMB + c0],     a0);
                unsafeAtomicAdd(&gs[cur * D_EMB + c0 + 1], a1);
            }
            cur = bb; a0 = 0.f; a1 = 0.f;
        }
        const unsigned u = *(const unsigned*)&state[(size_t)n * D_EMB + c0];
        a0 += bf2f(u & 0xffff);
        a1 += bf2f(u >> 16);
    }
    if (cur >= 0) {
        unsafeAtomicAdd(&gs[cur * D_EMB + c0],     a0);
        unsafeAtomicAdd(&gs[cur * D_EMB + c0 + 1], a1);
    }
}

__global__ __launch_bounds__(256) void out_kernel(
    const float* __restrict__ gs, const float* __restrict__ W,
    const float* __restrict__ bias, float* __restrict__ out)
{
    const int idx = blockIdx.x * 256 + threadIdx.x;
    const int g = idx >> 5;
    const int m = idx & 31;
    float acc = 0.f;
    #pragma unroll 8
    for (int k = 0; k < D_EMB; ++k)
        acc += gs[g * D_EMB + k] * W[k * M_OUT + m];
    out[idx] = acc + bias[m];
}

// ---------------------------------------------------------------------------
extern "C" void kernel_launch(void* const* d_in, const int* in_sizes, int n_in,
                              void* d_out, int out_size, void* d_ws, size_t ws_size,
                              hipStream_t stream)
{
    const float* x     = (const float*)d_in[0];
    const int*   eidx  = (const int*)d_in[1];
    const int*   batch = (const int*)d_in[2];
    const float* emb_W = (const float*)d_in[3];
    const float* emb_b = (const float*)d_in[4];
    const float* msg_W = (const float*)d_in[5];
    const float* msg_b = (const float*)d_in[6];
    const float* upd_W = (const float*)d_in[7];
    const float* upd_b = (const float*)d_in[8];
    const float* out_W = (const float*)d_in[9];
    const float* out_b = (const float*)d_in[10];
    float* out = (float*)d_out;

    const int* src = eidx;
    const int* dst = eidx + N_EDGES;

    // workspace: state | msg | agg (bf16, 25.6 MB each) | gs | WTall | rp | esrc | partials
    char* p = (char*)d_ws;
    unsigned short* state = (unsigned short*)p;   p += (size_t)N_NODES * D_EMB * 2;
    unsigned short* msg   = (unsigned short*)p;   p += (size_t)N_NODES * D_EMB * 2;
    unsigned short* agg   = (unsigned short*)p;   p += (size_t)N_NODES * D_EMB * 2;
    float* gs = (float*)p;                        p += (size_t)NUM_GRAPHS * D_EMB * 4;
    unsigned short* WTall = (unsigned short*)p;   p += (size_t)9 * D_EMB * D_EMB * 2;
    int* rp       = (int*)p;                      p += (size_t)(N_NODES + 1) * 4;
    int* esrc     = (int*)p;                      p += (size_t)N_EDGES * 4;
    int* partials = (int*)p;

    int* deg = (int*)msg;    // dead after scan_local
    int* pos = (int*)agg;    // dead after fill

    const dim3 blk(256);
    const int mp_grid = (N_EDGES / 256) * NPASS;   // 50000

    // ---- weight prep + CSR build ----
    prep_weights_kernel<<<9, blk, 0, stream>>>(emb_W, msg_W, upd_W, WTall);
    hipMemsetAsync(deg, 0, (size_t)N_NODES * sizeof(int), stream);
    hist_mp_kernel<<<mp_grid, blk, 0, stream>>>(dst, deg);
    scan_local_kernel<<<SCAN_NBLK, blk, 0, stream>>>(deg, rp, partials);
    scan_partials_kernel<<<1, 128, 0, stream>>>(partials);
    scan_fixup_kernel<<<(SCAN_NBLK * SCAN_ELEMS_PER_BLOCK) / 256, blk, 0, stream>>>(rp, partials, pos);
    fill_mp_kernel<<<mp_grid, blk, 0, stream>>>(src, dst, pos, esrc);

    // ---- network ----
    gemm_loop_kernel<2, true><<<GEMM_BLOCKS, blk, 0, stream>>>(
        x, WTall, emb_b, state, nullptr);

    for (int r = 0; r < ROUNDS; ++r) {
        gemm_loop_kernel<0, false><<<GEMM_BLOCKS, blk, 0, stream>>>(
            state, WTall + (size_t)(1 + r) * D_EMB * D_EMB,
            msg_b + (size_t)r * D_EMB, nullptr, msg);
        gather_bf16_kernel<<<(N_NODES + 15) / 16, blk, 0, stream>>>(
            msg, rp, esrc, agg);
        gemm_loop_kernel<1, false><<<GEMM_BLOCKS, blk, 0, stream>>>(
            agg, WTall + (size_t)(5 + r) * D_EMB * D_EMB,
            upd_b + (size_t)r * D_EMB, state, nullptr);
    }

    hipMemsetAsync(gs, 0, (size_t)NUM_GRAPHS * D_EMB * sizeof(float), stream);
    pool_kernel<<<(N_NODES + 127) / 128, blk, 0, stream>>>(state, batch, gs);
    out_kernel<<<(NUM_GRAPHS * M_OUT) / 256, blk, 0, stream>>>(gs, out_W, out_b, out);
}